// Round 9
// baseline (302.846 us; speedup 1.0000x reference)
//
#include <hip/hip_runtime.h>
#include <hip/hip_fp16.h>
#include <cstdint>

// GCN: chunk-local bucket partition -> per-bucket LDS counting-sort to CSR ->
// fp16-packed gather aggregation. GEMMs: bf16 MFMA, double-buffered swizzled
// LDS X staging, resident bf16 W^T, coalesced G stores via LDS transpose.

constexpr int CHUNK = 8192;   // edges per partition chunk
constexpr int BKCAP = 8192;   // max edges per 128-node bucket (mean 4096)

typedef __attribute__((ext_vector_type(8))) short bf16x8;
typedef __attribute__((ext_vector_type(4))) float f32x4;

__device__ __forceinline__ int cvt2bf(float a, float b) {
    int r;
    asm("v_cvt_pk_bf16_f32 %0, %1, %2" : "=v"(r) : "v"(a), "v"(b));  // non-volatile: schedulable
    return r;
}

// ---- P2: per-chunk bucket sort into pairs1 (chunk-grouped, packed 4B) ----
__global__ __launch_bounds__(256) void p2_localsort(
        const int* __restrict__ esrc, const int* __restrict__ edst, int E,
        unsigned* __restrict__ pairs1, int* __restrict__ cntMat,
        int* __restrict__ startMat, int NBK) {
    __shared__ int hist[1024];
    __shared__ int wsum[256];
    __shared__ unsigned lp[CHUNK];        // 32 KB
    const int t = threadIdx.x, blk = blockIdx.x;
    const int base = blk * CHUNK;
    const int cnt = min(CHUNK, E - base);
    for (int i = t; i < 1024; i += 256) hist[i] = 0;
    __syncthreads();
    for (int i = t; i < cnt; i += 256) atomicAdd(&hist[edst[base + i] >> 7], 1);
    __syncthreads();
    int h0 = hist[4*t], h1 = hist[4*t+1], h2 = hist[4*t+2], h3 = hist[4*t+3];
    int s = h0 + h1 + h2 + h3;
    wsum[t] = s; __syncthreads();
    #pragma unroll
    for (int o = 1; o < 256; o <<= 1) {
        int x = (t >= o) ? wsum[t - o] : 0;
        __syncthreads(); wsum[t] += x; __syncthreads();
    }
    int run = wsum[t] - s;
    int e0 = run, e1 = run + h0, e2 = e1 + h1, e3 = e2 + h2;
    hist[4*t] = e0; hist[4*t+1] = e1; hist[4*t+2] = e2; hist[4*t+3] = e3;
    if (4*t     < NBK) { cntMat[(size_t)blk*NBK + 4*t]     = h0; startMat[(size_t)blk*NBK + 4*t]     = e0; }
    if (4*t + 1 < NBK) { cntMat[(size_t)blk*NBK + 4*t + 1] = h1; startMat[(size_t)blk*NBK + 4*t + 1] = e1; }
    if (4*t + 2 < NBK) { cntMat[(size_t)blk*NBK + 4*t + 2] = h2; startMat[(size_t)blk*NBK + 4*t + 2] = e2; }
    if (4*t + 3 < NBK) { cntMat[(size_t)blk*NBK + 4*t + 3] = h3; startMat[(size_t)blk*NBK + 4*t + 3] = e3; }
    __syncthreads();
    for (int i = t; i < cnt; i += 256) {
        int d = edst[base + i];
        int pos = atomicAdd(&hist[d >> 7], 1);
        lp[pos] = ((unsigned)(d & 127) << 17) | (unsigned)esrc[base + i];
    }
    __syncthreads();
    for (int i = t; i < cnt; i += 256) pairs1[base + i] = lp[i];  // coalesced
}

// ---- P3: column-wise exclusive scan of cntMat over chunks; totals -> TB ----
__global__ __launch_bounds__(256) void p3_colscan(int* __restrict__ cntMat,
        int* __restrict__ TB, int nchunks, int NBK) {
    __shared__ int buf[512];
    const int t = threadIdx.x, b = blockIdx.x;
    int v0 = (t < nchunks) ? cntMat[(size_t)t*NBK + b] : 0;
    int v1 = (t + 256 < nchunks) ? cntMat[(size_t)(t + 256)*NBK + b] : 0;
    buf[t] = v0; buf[t + 256] = v1; __syncthreads();
    #pragma unroll
    for (int o = 1; o < 512; o <<= 1) {
        int x0 = (t >= o) ? buf[t - o] : 0;
        int x1 = (t + 256 >= o) ? buf[t + 256 - o] : 0;
        __syncthreads(); buf[t] += x0; buf[t + 256] += x1; __syncthreads();
    }
    if (t < nchunks) cntMat[(size_t)t*NBK + b] = buf[t] - v0;          // cumBefore
    if (t + 256 < nchunks) cntMat[(size_t)(t + 256)*NBK + b] = buf[t + 256] - v1;
    if (t == 0) TB[b] = buf[511];
}

// ---- P4: exclusive scan of TB -> bucketBase ----
__global__ __launch_bounds__(256) void p4_scan(const int* __restrict__ TB,
        int* __restrict__ bucketBase, int NBK, int E) {
    __shared__ int buf[1024];
    __shared__ int wsum[256];
    const int t = threadIdx.x;
    for (int i = t; i < 1024; i += 256) buf[i] = (i < NBK) ? TB[i] : 0;
    __syncthreads();
    int h0 = buf[4*t], h1 = buf[4*t+1], h2 = buf[4*t+2], h3 = buf[4*t+3];
    int s = h0 + h1 + h2 + h3;
    wsum[t] = s; __syncthreads();
    #pragma unroll
    for (int o = 1; o < 256; o <<= 1) {
        int x = (t >= o) ? wsum[t - o] : 0;
        __syncthreads(); wsum[t] += x; __syncthreads();
    }
    int run = wsum[t] - s;
    int e0 = run, e1 = run + h0, e2 = e1 + h1, e3 = e2 + h2;
    if (4*t     < NBK) bucketBase[4*t]     = e0;
    if (4*t + 1 < NBK) bucketBase[4*t + 1] = e1;
    if (4*t + 2 < NBK) bucketBase[4*t + 2] = e2;
    if (4*t + 3 < NBK) bucketBase[4*t + 3] = e3;
    if (t == 0) bucketBase[NBK] = E;
}

// ---- P6: per-bucket gather from pairs1 + LDS counting-sort by node ->
//      csrc (CSR order), rofs[node], dinv[node]. One block per bucket. ----
__global__ __launch_bounds__(256) void p6_sortcsr(
        const unsigned* __restrict__ pairs1, const int* __restrict__ cumMat,
        const int* __restrict__ startMat, const int* __restrict__ TB,
        const int* __restrict__ bucketBase, int nchunks, int NBK,
        int* __restrict__ csrc, int* __restrict__ rofs,
        float* __restrict__ dinv, int N, int E) {
    __shared__ unsigned lp[BKCAP];        // 32 KB
    __shared__ int ccum[512];
    __shared__ int cstart[512];
    __shared__ int hist[128];
    __shared__ int sc[128];
    __shared__ int foffs[128];
    const int t = threadIdx.x, b = blockIdx.x;
    const int total0 = TB[b];
    const int total = min(total0, BKCAP);
    const int base = bucketBase[b];
    for (int i = t; i < nchunks; i += 256) {
        ccum[i]   = cumMat[(size_t)i * NBK + b];
        cstart[i] = startMat[(size_t)i * NBK + b];
    }
    if (t < 128) hist[t] = 0;
    if (t == 0) ccum[nchunks] = total0;
    __syncthreads();
    for (int i = t; i < total; i += 256) {
        int lo = 0, hi = nchunks - 1;
        while (lo < hi) {
            int mid = (lo + hi + 1) >> 1;
            if (ccum[mid] <= i) lo = mid; else hi = mid - 1;
        }
        unsigned v = pairs1[(size_t)lo * CHUNK + cstart[lo] + (i - ccum[lo])];
        lp[i] = v;
        atomicAdd(&hist[v >> 17], 1);
    }
    __syncthreads();
    if (t < 128) sc[t] = hist[t];
    __syncthreads();
    #pragma unroll
    for (int o = 1; o < 128; o <<= 1) {
        int x = (t >= o && t < 128) ? sc[t - o] : 0;
        __syncthreads();
        if (t < 128) sc[t] += x;
        __syncthreads();
    }
    if (t < 128) {
        int excl = sc[t] - hist[t];
        foffs[t] = excl;
        int node = b * 128 + t;
        if (node < N) {
            rofs[node] = base + excl;
            dinv[node] = rsqrtf((float)hist[t] + 1.0f);   // +1 self-loop
        }
    }
    if (b == 0 && t == 255) rofs[N] = E;
    __syncthreads();
    for (int i = t; i < total; i += 256) {
        unsigned v = lp[i];
        int pos = atomicAdd(&foffs[v >> 17], 1);
        csrc[base + pos] = (int)(v & 0x1FFFFu);
    }
}

// ---- GEMM via bf16 MFMA, pipelined LDS staging ----
// Block: 256 thr (4 waves), 64-row x 64-col tile; wave w owns rows w*16..+16.
// K in BK=32 chunks. X chunk reg-staged -> ds_write_b128 into double-buffered
// LDS [64 rows][8 x 16B slots], slot XOR-swizzled by (row&7) -> both staging
// write and a_frag read are uniform 8-lanes/bank (conflict-free).
// W^T resident bf16 LDS [64][K+4] (stride 130 dw = 2 mod 32 -> conflict-free).
// Epilogue: D-frag -> wave-local LDS scratch (reuses X bufs) -> coalesced
// uint4 stores of fp16 G. dinv folded in before the cvt.
template<int K>
__global__ __launch_bounds__(256) void k_gemm(const float* __restrict__ X,
        const float* __restrict__ Wm, const float* __restrict__ dinv,
        __half* __restrict__ G, int nrows) {
    constexpr int KP  = K + 4;
    constexpr int NCH = K / 32;
    __shared__ unsigned short Wt[64 * KP];   // K=256: 33.3KB, K=64: 8.7KB
    __shared__ float Xs[2][64 * 32];         // 16KB double buffer
    const int t = threadIdx.x;
    // stage W^T as bf16 (coalesced reads: i = k*64 + n)
    for (int i = t; i < K * 64; i += 256) {
        int k = i >> 6, n = i & 63;
        Wt[n * KP + k] = (unsigned short)(cvt2bf(Wm[i], Wm[i]) & 0xFFFF);
    }
    const int l   = t & 63;
    const int w   = t >> 6;
    const int c16 = l & 15;
    const int g4  = l >> 4;
    const int brow = blockIdx.x * 64;

    // this thread's two staging slots: s = t + i*256 -> row = s>>3, kslot = s&7
    int srcoff[2], dstoff[2];
    #pragma unroll
    for (int i = 0; i < 2; ++i) {
        int s = t + i * 256;
        int row = s >> 3, ks = s & 7;
        int gr = min(brow + row, nrows - 1);
        srcoff[i] = gr * K + ks * 4;                      // + ch*32 at use
        dstoff[i] = row * 32 + ((ks ^ (row & 7)) << 2);   // swizzled float idx
    }

    // prologue: load ch0, write buf0; preload ch1 into regs
    float4 r0 = *(const float4*)(X + (size_t)srcoff[0]);
    float4 r1 = *(const float4*)(X + (size_t)srcoff[1]);
    *(float4*)(&Xs[0][dstoff[0]]) = r0;
    *(float4*)(&Xs[0][dstoff[1]]) = r1;
    if (NCH > 1) {
        r0 = *(const float4*)(X + (size_t)srcoff[0] + 32);
        r1 = *(const float4*)(X + (size_t)srcoff[1] + 32);
    }
    __syncthreads();

    f32x4 acc[4] = {{0,0,0,0},{0,0,0,0},{0,0,0,0},{0,0,0,0}};
    const int xrow = (w * 16 + c16) * 32;
    const int xsw  = (w * 16 + c16) & 7;

    for (int ch = 0; ch < NCH; ++ch) {
        if (ch + 1 < NCH) {                   // write next chunk (other buffer)
            *(float4*)(&Xs[(ch + 1) & 1][dstoff[0]]) = r0;
            *(float4*)(&Xs[(ch + 1) & 1][dstoff[1]]) = r1;
            if (ch + 2 < NCH) {               // prefetch chunk ch+2
                r0 = *(const float4*)(X + (size_t)srcoff[0] + (ch + 2) * 32);
                r1 = *(const float4*)(X + (size_t)srcoff[1] + (ch + 2) * 32);
            }
        }
        const float* xb = Xs[ch & 1];
        float4 u = *(const float4*)(xb + xrow + (((g4 * 2 + 0) ^ xsw) << 2));
        float4 v = *(const float4*)(xb + xrow + (((g4 * 2 + 1) ^ xsw) << 2));
        int4 ap;
        ap.x = cvt2bf(u.x, u.y); ap.y = cvt2bf(u.z, u.w);
        ap.z = cvt2bf(v.x, v.y); ap.w = cvt2bf(v.z, v.w);
        bf16x8 a = *(bf16x8*)&ap;
        #pragma unroll
        for (int cg = 0; cg < 4; ++cg) {
            bf16x8 bb = *(bf16x8*)(&Wt[(cg * 16 + c16) * KP + ch * 32 + g4 * 8]);
            acc[cg] = __builtin_amdgcn_mfma_f32_16x16x32_bf16(a, bb, acc[cg], 0, 0, 0);
        }
        __syncthreads();                      // next buffer ready / buffer free
    }

    // epilogue: scale by dinv, fp16 into wave-local LDS scratch, coalesced out
    __half* scr = (__half*)(&Xs[0][0]) + w * (16 * 72);   // 16 rows x 72 halves
    #pragma unroll
    for (int r = 0; r < 4; ++r) {
        int grow = brow + w * 16 + g4 * 4 + r;
        float dv = (grow < nrows) ? dinv[grow] : 0.f;
        #pragma unroll
        for (int cg = 0; cg < 4; ++cg)
            scr[(g4 * 4 + r) * 72 + cg * 16 + c16] = __float2half(acc[cg][r] * dv);
    }
    __syncthreads();                          // scratch visible + alias fence
    const int row16 = l >> 2, q = l & 3;
    const int grow = brow + w * 16 + row16;
    uint4 d0 = *(const uint4*)(scr + row16 * 72 + q * 16);
    uint4 d1 = *(const uint4*)(scr + row16 * 72 + q * 16 + 8);
    if (grow < nrows) {
        *(uint4*)(G + (size_t)grow * 64 + q * 16)     = d0;
        *(uint4*)(G + (size_t)grow * 64 + q * 16 + 8) = d1;
    }
}

// ---- Aggregate: H[d,:] = relu(dinv[d]*(G[d,:] + sum_{e in CSR[d]} G[src_e,:]) + b)
// One wave per node; 8 edge-slots x 8 lanes (uint4 = 16B = 8 fp16 features).
// fp16 packed accumulation; fp32 epilogue.
#define ACC8H(HA, V) { \
    HA[0] = __hadd2(HA[0], *(const __half2*)&(V).x); \
    HA[1] = __hadd2(HA[1], *(const __half2*)&(V).y); \
    HA[2] = __hadd2(HA[2], *(const __half2*)&(V).z); \
    HA[3] = __hadd2(HA[3], *(const __half2*)&(V).w); }

__global__ __launch_bounds__(256) void k_agg(const __half* __restrict__ G,
        const int* __restrict__ rofs, const int* __restrict__ csrc,
        const float* __restrict__ dinv, const float* __restrict__ bias,
        float* __restrict__ H, int nrows) {
    const int l = threadIdx.x & 63;
    const int g = l >> 3;                  // edge slot 0..7
    const int p = l & 7;                   // 16B chunk within row
    const int d = blockIdx.x * 4 + (threadIdx.x >> 6);
    if (d >= nrows) return;                // wave-uniform
    const int beg = rofs[d], end = rofs[d + 1];
    __half2 ha[4];
    #pragma unroll
    for (int q = 0; q < 4; ++q) ha[q] = __half2(__float2half(0.f), __float2half(0.f));

    int e = beg + g;
    for (; e + 8 < end; e += 16) {         // 2 edges in flight per slot
        int s0 = csrc[e];
        int s1 = csrc[e + 8];
        uint4 v0 = *(const uint4*)(G + (size_t)s0 * 64 + p * 8);
        uint4 v1 = *(const uint4*)(G + (size_t)s1 * 64 + p * 8);
        ACC8H(ha, v0)
        ACC8H(ha, v1)
    }
    if (e < end) {
        int s = csrc[e];
        uint4 v = *(const uint4*)(G + (size_t)s * 64 + p * 8);
        ACC8H(ha, v)
    }
    #pragma unroll
    for (int off = 8; off <= 32; off <<= 1) {
        #pragma unroll
        for (int q = 0; q < 4; ++q) {
            int o = __shfl_xor(*(int*)&ha[q], off);
            ha[q] = __hadd2(ha[q], *(__half2*)&o);
        }
    }
    if (g == 0) {
        float2 a0 = __half22float2(ha[0]), a1 = __half22float2(ha[1]);
        float2 a2 = __half22float2(ha[2]), a3 = __half22float2(ha[3]);
        uint4 sv = *(const uint4*)(G + (size_t)d * 64 + p * 8);
        float2 s0 = __half22float2(*(const __half2*)&sv.x);
        float2 s1 = __half22float2(*(const __half2*)&sv.y);
        float2 s2 = __half22float2(*(const __half2*)&sv.z);
        float2 s3 = __half22float2(*(const __half2*)&sv.w);
        const float dv = dinv[d];
        const float4* B4 = (const float4*)bias;
        float4 b0 = B4[p * 2], b1 = B4[p * 2 + 1];
        float4 o0, o1;
        o0.x = fmaxf((a0.x + s0.x) * dv + b0.x, 0.f);
        o0.y = fmaxf((a0.y + s0.y) * dv + b0.y, 0.f);
        o0.z = fmaxf((a1.x + s1.x) * dv + b0.z, 0.f);
        o0.w = fmaxf((a1.y + s1.y) * dv + b0.w, 0.f);
        o1.x = fmaxf((a2.x + s2.x) * dv + b1.x, 0.f);
        o1.y = fmaxf((a2.y + s2.y) * dv + b1.y, 0.f);
        o1.z = fmaxf((a3.x + s3.x) * dv + b1.z, 0.f);
        o1.w = fmaxf((a3.y + s3.y) * dv + b1.w, 0.f);
        float4* H4 = (float4*)(H + (size_t)d * 64 + p * 8);
        H4[0] = o0; H4[1] = o1;
    }
}

// ---- Head: out[row,:] = log_softmax(H[row,:] @ W3 + b3), OUT=40 ----
__global__ __launch_bounds__(256) void k_final(const float* __restrict__ H,
        const float* __restrict__ W3, const float* __restrict__ b3,
        float* __restrict__ out, int nrows) {
    constexpr int HP = 68;
    constexpr int OP = 44;
    __shared__ float wl[64 * 40];
    __shared__ float bl[40];
    __shared__ float Hs[256 * HP];
    const int t = threadIdx.x;
    for (int i = t; i < 640; i += 256)
        ((float4*)wl)[i] = ((const float4*)W3)[i];
    if (t < 40) bl[t] = b3[t];
    const int brow = blockIdx.x * 256;
    const int rows = min(256, nrows - brow);
    for (int i = t; i < rows * 16; i += 256) {
        int r = i >> 4, c = i & 15;
        float4 v = ((const float4*)(H + (size_t)(brow + r) * 64))[c];
        *(float4*)&Hs[r * HP + c * 4] = v;
    }
    __syncthreads();

    float acc[40];
    float lse = 0.f;
    if (t < rows) {
        #pragma unroll
        for (int j = 0; j < 40; ++j) acc[j] = bl[j];
        #pragma unroll
        for (int k4 = 0; k4 < 16; ++k4) {
            float4 h4 = *(const float4*)&Hs[t * HP + k4 * 4];
            float hv[4] = {h4.x, h4.y, h4.z, h4.w};
            #pragma unroll
            for (int c = 0; c < 4; ++c) {
                const float4* wr = (const float4*)(wl + (k4 * 4 + c) * 40);
                #pragma unroll
                for (int j4 = 0; j4 < 10; ++j4) {
                    float4 wv = wr[j4];
                    acc[j4 * 4 + 0] += hv[c] * wv.x;
                    acc[j4 * 4 + 1] += hv[c] * wv.y;
                    acc[j4 * 4 + 2] += hv[c] * wv.z;
                    acc[j4 * 4 + 3] += hv[c] * wv.w;
                }
            }
        }
        float m = acc[0];
        #pragma unroll
        for (int j = 1; j < 40; ++j) m = fmaxf(m, acc[j]);
        float s = 0.f;
        #pragma unroll
        for (int j = 0; j < 40; ++j) s += expf(acc[j] - m);
        lse = m + logf(s);
    }
    __syncthreads();
    float* Os = Hs;
    if (t < rows) {
        #pragma unroll
        for (int j4 = 0; j4 < 10; ++j4)
            *(float4*)&Os[t * OP + j4 * 4] =
                make_float4(acc[j4 * 4 + 0] - lse, acc[j4 * 4 + 1] - lse,
                            acc[j4 * 4 + 2] - lse, acc[j4 * 4 + 3] - lse);
    }
    __syncthreads();
    for (int i = t; i < rows * 40; i += 256) {
        int r = i / 40, c = i - r * 40;
        out[(size_t)brow * 40 + i] = Os[r * OP + c];
    }
}

extern "C" void kernel_launch(void* const* d_in, const int* in_sizes, int n_in,
                              void* d_out, int out_size, void* d_ws, size_t ws_size,
                              hipStream_t stream) {
    const float* x  = (const float*)d_in[0];
    const int*   ei = (const int*)d_in[1];     // [2][E]: row0=src, row1=dst
    const float* W1 = (const float*)d_in[2];
    const float* b1 = (const float*)d_in[3];
    const float* W2 = (const float*)d_in[4];
    const float* b2 = (const float*)d_in[5];
    const float* W3 = (const float*)d_in[6];
    const float* b3 = (const float*)d_in[7];
    float* out = (float*)d_out;

    const int HID = in_sizes[3];            // 64
    const int IND = in_sizes[2] / HID;      // 256
    const int N   = in_sizes[0] / IND;      // 100000
    const int E   = in_sizes[1] / 2;        // 3200000
    (void)HID; (void)n_in; (void)out_size; (void)ws_size;

    const int NBK     = (N + 127) >> 7;             // 782
    const int nchunks = (E + CHUNK - 1) / CHUNK;    // 391

    char* ws = (char*)d_ws;
    size_t off = 0;
    auto alloc = [&](size_t bytes) -> char* {
        char* p = ws + off;
        off = (off + bytes + 255) & ~(size_t)255;
        return p;
    };
    size_t gbytes = (size_t)N * 64 * 2;             // fp16 G
    size_t p1bytes = (size_t)E * 4;                 // pairs1 overlay
    int*      cntMat     = (int*)     alloc((size_t)nchunks * NBK * 4);
    int*      startMat   = (int*)     alloc((size_t)nchunks * NBK * 4);
    int*      TB         = (int*)     alloc((size_t)NBK * 4);
    int*      bucketBase = (int*)     alloc(((size_t)NBK + 1) * 4);
    float*    dinv       = (float*)   alloc((size_t)N * 4);
    int*      rofs       = (int*)     alloc(((size_t)N + 1) * 4);
    int*      csrc       = (int*)     alloc((size_t)E * 4);
    __half*   g          = (__half*)  alloc(gbytes > p1bytes ? gbytes : p1bytes);
    float*    h          = (float*)   alloc((size_t)N * 64 * 4);
    unsigned* pairs1     = (unsigned*)g;    // overlay: dead before gemm1 writes g

    const int* esrc = ei;
    const int* edst = ei + E;
    const int gM = (N + 63) / 64;           // 1563
    const int gN = (N + 255) / 256;

    p2_localsort<<<nchunks, 256, 0, stream>>>(esrc, edst, E, pairs1, cntMat, startMat, NBK);
    p3_colscan  <<<NBK, 256, 0, stream>>>(cntMat, TB, nchunks, NBK);
    p4_scan     <<<1, 256, 0, stream>>>(TB, bucketBase, NBK, E);
    p6_sortcsr  <<<NBK, 256, 0, stream>>>(pairs1, cntMat, startMat, TB, bucketBase,
                                          nchunks, NBK, csrc, rofs, dinv, N, E);

    k_gemm<256> <<<gM, 256, 0, stream>>>(x, W1, dinv, g, N);
    k_agg       <<<(N + 3) / 4, 256, 0, stream>>>(g, rofs, csrc, dinv, b1, h, N);
    k_gemm<64>  <<<gM, 256, 0, stream>>>(h, W2, dinv, g, N);
    k_agg       <<<(N + 3) / 4, 256, 0, stream>>>(g, rofs, csrc, dinv, b2, h, N);
    k_final     <<<gN, 256, 0, stream>>>(h, W3, b3, out, N);
}